// Round 2
// baseline (86.235 us; speedup 1.0000x reference)
//
#include <hip/hip_runtime.h>

namespace {
constexpr int NPTS = 16384;
constexpr int CH   = 64;
constexpr int KNN  = 16;
constexpr int ROWS = 8 * NPTS;
constexpr float EPS = 1e-5f;
}

typedef __attribute__((ext_vector_type(8))) short  short8;
typedef __attribute__((ext_vector_type(4))) float  f32x4;
typedef __attribute__((ext_vector_type(4))) unsigned uint4v;
typedef __attribute__((ext_vector_type(2))) unsigned uint2v;
typedef __attribute__((ext_vector_type(4))) int    int4v;

static __device__ __forceinline__ unsigned pk_bf16(float lo, float hi) {
    unsigned r;
    asm("v_cvt_pk_bf16_f32 %0, %1, %2" : "=v"(r) : "v"(lo), "v"(hi));
    return r;
}

static __device__ __host__ __forceinline__ unsigned f2bf(float f) {
    unsigned u = __builtin_bit_cast(unsigned, f);
    return (u + 0x7fffu + ((u >> 16) & 1u)) >> 16;   // RNE; W values are normal
}

// Precompute W as bf16 B-fragments in exact per-lane order.
// frag f = ct*2 + kh (ct: 16-col tile of OUT, kh: K half).
// lane l, elem j -> B[k = kh*32 + (l>>4)*8 + j][n = ct*16 + (l&15)]
__global__ __launch_bounds__(64)
void k_prep(const float* __restrict__ W, unsigned* __restrict__ wsb)
{
    const int l = threadIdx.x;
    const int nq = l >> 4, nr = l & 15;
#pragma unroll
    for (int ct = 0; ct < 4; ++ct)
#pragma unroll
        for (int kh = 0; kh < 2; ++kh) {
            uint4v d;
#pragma unroll
            for (int dj = 0; dj < 4; ++dj) {
                const int k0 = kh * 32 + nq * 8 + dj * 2;
                unsigned lo = f2bf(W[(size_t)k0 * CH + ct * 16 + nr]);
                unsigned hi = f2bf(W[(size_t)(k0 + 1) * CH + ct * 16 + nr]);
                d[dj] = lo | (hi << 16);
            }
            ((uint4v*)wsb)[(ct * 2 + kh) * 64 + l] = d;
        }
}

// K1: gather -> max(seed 0 == relu) -> bf16 -> LDS A-tile -> MFMA -> y + stats.
// One 16-row tile per wave. Per-wave-private LDS (no intra-loop syncthreads).
__global__ __launch_bounds__(256)
void k_fused(const float* __restrict__ x, const int* __restrict__ idx,
             const unsigned* __restrict__ wsb, float* __restrict__ y,
             float* __restrict__ stats)
{
    __shared__ __align__(16) ushort Atile[4][16 * 64];   // per-wave 16x64 bf16, XOR-swizzled
    __shared__ __align__(16) int    Ibuf[4][256];        // per-wave 16x16 idx
    __shared__ float bs1[64], bs2[64];

    const int lane  = threadIdx.x & 63;
    const int wave  = threadIdx.x >> 6;
    const int batch = blockIdx.x & 7;                    // XCD-aligned: batch slab stays in one L2
    const int chunk = blockIdx.x >> 3;

    if (threadIdx.x < 64)       bs1[threadIdx.x] = 0.f;
    else if (threadIdx.x < 128) bs2[threadIdx.x - 64] = 0.f;
    __syncthreads();

    const int r0 = chunk * 64 + wave * 16;               // tile start row within batch
    const float* __restrict__ xb = x   + (size_t)batch * NPTS * CH;
    const int*   __restrict__ ib = idx + (size_t)batch * NPTS * KNN;
    float*       __restrict__ yb = y   + (size_t)batch * NPTS * CH;

    const int c4 = lane & 15;
    const int qq = lane >> 4;

    // stage this tile's 256 neighbor indices into LDS (1 int4 per lane)
    int4v iq = ((const int4v*)(ib + (size_t)r0 * KNN))[lane];
    *(int4v*)&Ibuf[wave][lane * 4] = iq;

    // B fragments (8 coalesced dwordx4 from precomputed ws)
    short8 bfr[8];
#pragma unroll
    for (int f = 0; f < 8; ++f)
        bfr[f] = __builtin_bit_cast(short8, ((const uint4v*)wsb)[f * 64 + lane]);

    char* aw = (char*)&Atile[wave][0];
    const f32x4* xb4 = (const f32x4*)xb;

    // gather+max: 4 rows at a time; quarter q owns row 4g+q, lanes 0-15 = 4-ch float4
#pragma unroll
    for (int g = 0; g < 4; ++g) {
        const int row = 4 * g + qq;
        const int* ip = &Ibuf[wave][row * KNN];
        f32x4 acc = {0.f, 0.f, 0.f, 0.f};                // seed 0 == fused relu
#pragma unroll
        for (int j = 0; j < KNN; ++j) {
            const int n = ip[j];                          // ds_read_b32 broadcast per quarter
            f32x4 v = xb4[n * 16 + c4];                   // 256B/row, fully coalesced
            acc[0] = fmaxf(acc[0], v[0]);
            acc[1] = fmaxf(acc[1], v[1]);
            acc[2] = fmaxf(acc[2], v[2]);
            acc[3] = fmaxf(acc[3], v[3]);
        }
        uint2v pw = { pk_bf16(acc[0], acc[1]), pk_bf16(acc[2], acc[3]) };
        const int wb = ((row * 128) + c4 * 8) ^ ((row & 7) << 4);   // XOR-swizzle
        *(uint2v*)(aw + wb) = pw;
    }

    // A fragments: row = lane&15, k = (lane>>4)*8 + j (+32 for kh=1)
    const int key = (c4 & 7) << 4;
    short8 a0 = *(const short8*)(aw + ((c4 * 128 + qq * 16) ^ key));
    short8 a1 = *(const short8*)(aw + ((c4 * 128 + 64 + qq * 16) ^ key));

    f32x4 acc0 = {0.f,0.f,0.f,0.f}, acc1 = {0.f,0.f,0.f,0.f};
    f32x4 acc2 = {0.f,0.f,0.f,0.f}, acc3 = {0.f,0.f,0.f,0.f};
    acc0 = __builtin_amdgcn_mfma_f32_16x16x32_bf16(a0, bfr[0], acc0, 0, 0, 0);
    acc0 = __builtin_amdgcn_mfma_f32_16x16x32_bf16(a1, bfr[1], acc0, 0, 0, 0);
    acc1 = __builtin_amdgcn_mfma_f32_16x16x32_bf16(a0, bfr[2], acc1, 0, 0, 0);
    acc1 = __builtin_amdgcn_mfma_f32_16x16x32_bf16(a1, bfr[3], acc1, 0, 0, 0);
    acc2 = __builtin_amdgcn_mfma_f32_16x16x32_bf16(a0, bfr[4], acc2, 0, 0, 0);
    acc2 = __builtin_amdgcn_mfma_f32_16x16x32_bf16(a1, bfr[5], acc2, 0, 0, 0);
    acc3 = __builtin_amdgcn_mfma_f32_16x16x32_bf16(a0, bfr[6], acc3, 0, 0, 0);
    acc3 = __builtin_amdgcn_mfma_f32_16x16x32_bf16(a1, bfr[7], acc3, 0, 0, 0);

    // C/D: col = ct*16 + (lane&15), row = (lane>>4)*4 + reg  [HW-verified layout]
    float* yrow = yb + (size_t)(r0 + qq * 4) * CH + c4;

#define DO_CT(CT, ACC)                                                          \
    {                                                                           \
        yrow[0 * CH + CT * 16] = ACC[0];                                        \
        yrow[1 * CH + CT * 16] = ACC[1];                                        \
        yrow[2 * CH + CT * 16] = ACC[2];                                        \
        yrow[3 * CH + CT * 16] = ACC[3];                                        \
        float s1 = (ACC[0] + ACC[1]) + (ACC[2] + ACC[3]);                       \
        float s2 = (ACC[0]*ACC[0] + ACC[1]*ACC[1]) + (ACC[2]*ACC[2] + ACC[3]*ACC[3]); \
        s1 += __shfl_xor(s1, 16); s1 += __shfl_xor(s1, 32);                     \
        s2 += __shfl_xor(s2, 16); s2 += __shfl_xor(s2, 32);                     \
        if (lane < 16) {                                                        \
            atomicAdd(&bs1[CT * 16 + lane], s1);                                \
            atomicAdd(&bs2[CT * 16 + lane], s2);                                \
        }                                                                       \
    }
    DO_CT(0, acc0) DO_CT(1, acc1) DO_CT(2, acc2) DO_CT(3, acc3)
#undef DO_CT

    __syncthreads();
    if (threadIdx.x < 64)        atomicAdd(&stats[threadIdx.x], bs1[threadIdx.x]);
    else if (threadIdx.x < 128)  atomicAdd(&stats[threadIdx.x], bs2[threadIdx.x - 64]);
}

// K2: finalize BN scale/bias (64 columns)
__global__ void k_finalize(const float* __restrict__ stats,
                           const float* __restrict__ gamma,
                           const float* __restrict__ beta,
                           float* __restrict__ sb)
{
    const int l = threadIdx.x;
    if (l >= CH) return;
    const float inv_n = 1.0f / (float)ROWS;
    float mean = stats[l] * inv_n;
    float ex2  = stats[64 + l] * inv_n;
    float var  = ex2 - mean * mean;
    float scale = gamma[l] * rsqrtf(var + EPS);
    sb[l]      = scale;
    sb[64 + l] = beta[l] - mean * scale;
}

// K3: in-place normalize y (float4, grid-stride)
__global__ __launch_bounds__(256)
void k_norm(float* __restrict__ y, const float* __restrict__ sb)
{
    __shared__ float s[CH], b[CH];
    if (threadIdx.x < CH) {
        s[threadIdx.x] = sb[threadIdx.x];
        b[threadIdx.x] = sb[64 + threadIdx.x];
    }
    __syncthreads();

    float4* p = (float4*)y;
    const size_t ntot = (size_t)ROWS * CH / 4;
    size_t i = (size_t)blockIdx.x * blockDim.x + threadIdx.x;
    const size_t stride = (size_t)gridDim.x * blockDim.x;
    for (; i < ntot; i += stride) {
        float4 v = p[i];
        const int c0 = ((int)i & 15) * 4;
        v.x = fmaf(v.x, s[c0],     b[c0]);
        v.y = fmaf(v.y, s[c0 + 1], b[c0 + 1]);
        v.z = fmaf(v.z, s[c0 + 2], b[c0 + 2]);
        v.w = fmaf(v.w, s[c0 + 3], b[c0 + 3]);
        p[i] = v;
    }
}

extern "C" void kernel_launch(void* const* d_in, const int* in_sizes, int n_in,
                              void* d_out, int out_size, void* d_ws, size_t ws_size,
                              hipStream_t stream)
{
    const float* x     = (const float*)d_in[0];
    const int*   idx   = (const int*)d_in[1];
    const float* W     = (const float*)d_in[2];
    const float* gamma = (const float*)d_in[3];
    const float* beta  = (const float*)d_in[4];

    float*    y     = (float*)d_out;
    float*    stats = (float*)d_ws;            // [0,64) sum, [64,128) sumsq
    float*    sb    = stats + 128;             // [0,64) scale, [64,128) bias
    unsigned* wsb   = (unsigned*)(stats + 256);// 8KB B-fragments

    hipMemsetAsync(stats, 0, 128 * sizeof(float), stream);
    k_prep<<<dim3(1), dim3(64), 0, stream>>>(W, wsb);
    k_fused<<<dim3(2048), dim3(256), 0, stream>>>(x, idx, wsb, y, stats);
    k_finalize<<<dim3(1), dim3(64), 0, stream>>>(stats, gamma, beta, sb);
    k_norm<<<dim3(2048), dim3(256), 0, stream>>>(y, sb);
}

// Round 3
// 70.412 us; speedup vs baseline: 1.2247x; 1.2247x over previous
//
#include <hip/hip_runtime.h>

namespace {
constexpr int NPTS = 16384;
constexpr int CH   = 64;
constexpr int KNN  = 16;
constexpr int ROWS = 8 * NPTS;
constexpr float EPS = 1e-5f;
}

typedef __attribute__((ext_vector_type(8))) short  short8;
typedef __attribute__((ext_vector_type(4))) float  f32x4;
typedef __attribute__((ext_vector_type(4))) unsigned uint4v;
typedef __attribute__((ext_vector_type(2))) unsigned uint2v;
typedef __attribute__((ext_vector_type(4))) int    int4v;

static __device__ __forceinline__ unsigned pk_bf16(float lo, float hi) {
    unsigned r;
    asm("v_cvt_pk_bf16_f32 %0, %1, %2" : "=v"(r) : "v"(lo), "v"(hi));
    return r;
}

static __device__ __host__ __forceinline__ unsigned f2bf(float f) {
    unsigned u = __builtin_bit_cast(unsigned, f);
    return (u + 0x7fffu + ((u >> 16) & 1u)) >> 16;   // RNE
}

// ---- W -> bf16 B-fragments (per-lane MFMA order), 8KB in ws ----
// frag f = ct*2 + kh; lane l elem j -> B[k = kh*32 + (l>>4)*8 + j][n = ct*16 + (l&15)]
__global__ __launch_bounds__(64)
void k_prep(const float* __restrict__ W, unsigned* __restrict__ wsb)
{
    const int l = threadIdx.x;
    const int nq = l >> 4, nr = l & 15;
#pragma unroll
    for (int ct = 0; ct < 4; ++ct)
#pragma unroll
        for (int kh = 0; kh < 2; ++kh) {
            uint4v d;
#pragma unroll
            for (int dj = 0; dj < 4; ++dj) {
                const int k0 = kh * 32 + nq * 8 + dj * 2;
                unsigned lo = f2bf(W[(size_t)k0 * CH + ct * 16 + nr]);
                unsigned hi = f2bf(W[(size_t)(k0 + 1) * CH + ct * 16 + nr]);
                d[dj] = lo | (hi << 16);
            }
            ((uint4v*)wsb)[(ct * 2 + kh) * 64 + l] = d;
        }
}

// ---- x (f32) -> bf16 rows of 128B, XCD-pinned so each batch slab lands in its own L2 ----
__global__ __launch_bounds__(256)
void k_cvt(const float* __restrict__ x, unsigned* __restrict__ xb16)
{
    const int batch = blockIdx.x & 7;
    const int chunk = blockIdx.x >> 3;          // 0..255, 64 rows each
    const int lane8 = threadIdx.x & 7;
    const int rr    = threadIdx.x >> 3;         // 0..31
    const float*  xb = x    + (size_t)batch * NPTS * CH;
    unsigned*     ob = xb16 + (size_t)batch * NPTS * 32;
#pragma unroll
    for (int h = 0; h < 2; ++h) {
        const int row = chunk * 64 + h * 32 + rr;
        const f32x4* src = (const f32x4*)(xb + (size_t)row * CH + lane8 * 8);
        f32x4 v0 = src[0], v1 = src[1];
        uint4v d;
        d[0] = pk_bf16(v0[0], v0[1]);
        d[1] = pk_bf16(v0[2], v0[3]);
        d[2] = pk_bf16(v1[0], v1[1]);
        d[3] = pk_bf16(v1[2], v1[3]);
        *(uint4v*)(ob + (size_t)row * 32 + lane8 * 4) = d;
    }
}

// ---- main fused kernel: bf16 gather -> max(seed 0 == relu) -> MFMA -> y + stats ----
// 8 lane-groups of 8; group g owns tile rows g and g+8 (8 channels/lane).
template<int NT>
__global__ __launch_bounds__(256, 4)
void k_fused_bf16(const unsigned* __restrict__ xb16, const int* __restrict__ idx,
                  const unsigned* __restrict__ wsb, float* __restrict__ y,
                  float* __restrict__ stats)
{
    __shared__ __align__(16) ushort   Atile[4][16 * 64];  // per-wave, XOR-swizzled
    __shared__ __align__(16) int      Ibuf[4][256];
    __shared__ __align__(16) unsigned Blds[2048];         // 8KB B-fragments
    __shared__ float bs1[64], bs2[64];

    const int lane  = threadIdx.x & 63;
    const int wave  = threadIdx.x >> 6;
    const int batch = blockIdx.x & 7;                     // XCD-aligned
    const int chunk = blockIdx.x >> 3;

    ((uint4v*)Blds)[threadIdx.x]       = ((const uint4v*)wsb)[threadIdx.x];
    ((uint4v*)Blds)[threadIdx.x + 256] = ((const uint4v*)wsb)[threadIdx.x + 256];
    if (threadIdx.x < 64)       bs1[threadIdx.x] = 0.f;
    else if (threadIdx.x < 128) bs2[threadIdx.x - 64] = 0.f;
    __syncthreads();

    const unsigned* __restrict__ xb = xb16 + (size_t)batch * NPTS * 32;
    const int*      __restrict__ ib = idx  + (size_t)batch * NPTS * KNN;
    float*          __restrict__ yb = y    + (size_t)batch * NPTS * CH;

    const int c4 = lane & 15, qq = lane >> 4;
    const int g8 = lane >> 3, c8 = lane & 7;
    char* aw = (char*)&Atile[wave][0];

    int r0 = chunk * (NT * 64) + wave * 16;
    int4v iq = ((const int4v*)(ib + (size_t)r0 * KNN))[lane];

#pragma unroll
    for (int it = 0; it < NT; ++it) {
        *(int4v*)&Ibuf[wave][lane * 4] = iq;
        if (it + 1 < NT) iq = ((const int4v*)(ib + (size_t)(r0 + 64) * KNN))[lane];

        const int* ipA = &Ibuf[wave][g8 * KNN];
        const int* ipB = &Ibuf[wave][(g8 + 8) * KNN];

        float aA[8], aB[8];
#pragma unroll
        for (int i = 0; i < 8; ++i) { aA[i] = 0.f; aB[i] = 0.f; }   // seed 0 == relu

#pragma unroll
        for (int j = 0; j < KNN; ++j) {
            const unsigned nA = (unsigned)ipA[j];
            const unsigned nB = (unsigned)ipB[j];
            uint4v vA = *(const uint4v*)(xb + (size_t)nA * 32 + c8 * 4);
            uint4v vB = *(const uint4v*)(xb + (size_t)nB * 32 + c8 * 4);
#pragma unroll
            for (int d = 0; d < 4; ++d) {
                aA[2*d]   = fmaxf(aA[2*d],   __uint_as_float(vA[d] << 16));
                aA[2*d+1] = fmaxf(aA[2*d+1], __uint_as_float(vA[d] & 0xffff0000u));
                aB[2*d]   = fmaxf(aB[2*d],   __uint_as_float(vB[d] << 16));
                aB[2*d+1] = fmaxf(aB[2*d+1], __uint_as_float(vB[d] & 0xffff0000u));
            }
        }

        // repack (values are exact bf16<<16 bit patterns) and write A-tile
        uint4v pA, pB;
#pragma unroll
        for (int d = 0; d < 4; ++d) {
            pA[d] = __float_as_uint(aA[2*d+1]) | (__float_as_uint(aA[2*d]) >> 16);
            pB[d] = __float_as_uint(aB[2*d+1]) | (__float_as_uint(aB[2*d]) >> 16);
        }
        const int colx = c8 * 16;
        *(uint4v*)(aw + ((g8 * 128 + colx) ^ (g8 << 4)))        = pA;
        *(uint4v*)(aw + (((g8 + 8) * 128 + colx) ^ (g8 << 4)))  = pB;

        // A fragments: row = lane&15, k = (lane>>4)*8 + j (+32 for second)
        const int key = (c4 & 7) << 4;
        short8 a0 = *(const short8*)(aw + ((c4 * 128 + qq * 16) ^ key));
        short8 a1 = *(const short8*)(aw + ((c4 * 128 + 64 + qq * 16) ^ key));

        short8 bfr[8];
#pragma unroll
        for (int f = 0; f < 8; ++f)
            bfr[f] = __builtin_bit_cast(short8, ((const uint4v*)Blds)[f * 64 + lane]);

        f32x4 acc0 = {0,0,0,0}, acc1 = {0,0,0,0}, acc2 = {0,0,0,0}, acc3 = {0,0,0,0};
        acc0 = __builtin_amdgcn_mfma_f32_16x16x32_bf16(a0, bfr[0], acc0, 0, 0, 0);
        acc0 = __builtin_amdgcn_mfma_f32_16x16x32_bf16(a1, bfr[1], acc0, 0, 0, 0);
        acc1 = __builtin_amdgcn_mfma_f32_16x16x32_bf16(a0, bfr[2], acc1, 0, 0, 0);
        acc1 = __builtin_amdgcn_mfma_f32_16x16x32_bf16(a1, bfr[3], acc1, 0, 0, 0);
        acc2 = __builtin_amdgcn_mfma_f32_16x16x32_bf16(a0, bfr[4], acc2, 0, 0, 0);
        acc2 = __builtin_amdgcn_mfma_f32_16x16x32_bf16(a1, bfr[5], acc2, 0, 0, 0);
        acc3 = __builtin_amdgcn_mfma_f32_16x16x32_bf16(a0, bfr[6], acc3, 0, 0, 0);
        acc3 = __builtin_amdgcn_mfma_f32_16x16x32_bf16(a1, bfr[7], acc3, 0, 0, 0);

        // C/D: col = ct*16 + (lane&15), row = (lane>>4)*4 + reg  [HW-verified]
        float* yrow = yb + (size_t)(r0 + qq * 4) * CH + c4;

#define DO_CT(CT, ACC)                                                              \
        {                                                                           \
            yrow[0 * CH + CT * 16] = ACC[0];                                        \
            yrow[1 * CH + CT * 16] = ACC[1];                                        \
            yrow[2 * CH + CT * 16] = ACC[2];                                        \
            yrow[3 * CH + CT * 16] = ACC[3];                                        \
            float s1 = (ACC[0] + ACC[1]) + (ACC[2] + ACC[3]);                       \
            float s2 = (ACC[0]*ACC[0] + ACC[1]*ACC[1]) + (ACC[2]*ACC[2] + ACC[3]*ACC[3]); \
            s1 += __shfl_xor(s1, 16); s1 += __shfl_xor(s1, 32);                     \
            s2 += __shfl_xor(s2, 16); s2 += __shfl_xor(s2, 32);                     \
            if (lane < 16) {                                                        \
                atomicAdd(&bs1[CT * 16 + lane], s1);                                \
                atomicAdd(&bs2[CT * 16 + lane], s2);                                \
            }                                                                       \
        }
        DO_CT(0, acc0) DO_CT(1, acc1) DO_CT(2, acc2) DO_CT(3, acc3)
#undef DO_CT

        r0 += 64;
    }

    __syncthreads();
    if (threadIdx.x < 64)        atomicAdd(&stats[threadIdx.x], bs1[threadIdx.x]);
    else if (threadIdx.x < 128)  atomicAdd(&stats[threadIdx.x], bs2[threadIdx.x - 64]);
}

// ---- fallback (ws too small): round-2 f32-gather kernel, known-correct ----
__global__ __launch_bounds__(256)
void k_fused_f32(const float* __restrict__ x, const int* __restrict__ idx,
                 const unsigned* __restrict__ wsb, float* __restrict__ y,
                 float* __restrict__ stats)
{
    __shared__ __align__(16) ushort Atile[4][16 * 64];
    __shared__ __align__(16) int    Ibuf[4][256];
    __shared__ float bs1[64], bs2[64];

    const int lane  = threadIdx.x & 63;
    const int wave  = threadIdx.x >> 6;
    const int batch = blockIdx.x & 7;
    const int chunk = blockIdx.x >> 3;

    if (threadIdx.x < 64)       bs1[threadIdx.x] = 0.f;
    else if (threadIdx.x < 128) bs2[threadIdx.x - 64] = 0.f;
    __syncthreads();

    const int r0 = chunk * 64 + wave * 16;
    const float* __restrict__ xb = x   + (size_t)batch * NPTS * CH;
    const int*   __restrict__ ib = idx + (size_t)batch * NPTS * KNN;
    float*       __restrict__ yb = y   + (size_t)batch * NPTS * CH;

    const int c4 = lane & 15;
    const int qq = lane >> 4;

    int4v iq = ((const int4v*)(ib + (size_t)r0 * KNN))[lane];
    *(int4v*)&Ibuf[wave][lane * 4] = iq;

    short8 bfr[8];
#pragma unroll
    for (int f = 0; f < 8; ++f)
        bfr[f] = __builtin_bit_cast(short8, ((const uint4v*)wsb)[f * 64 + lane]);

    char* aw = (char*)&Atile[wave][0];
    const f32x4* xb4 = (const f32x4*)xb;

#pragma unroll
    for (int g = 0; g < 4; ++g) {
        const int row = 4 * g + qq;
        const int* ip = &Ibuf[wave][row * KNN];
        f32x4 acc = {0.f, 0.f, 0.f, 0.f};
#pragma unroll
        for (int j = 0; j < KNN; ++j) {
            const int n = ip[j];
            f32x4 v = xb4[n * 16 + c4];
            acc[0] = fmaxf(acc[0], v[0]);
            acc[1] = fmaxf(acc[1], v[1]);
            acc[2] = fmaxf(acc[2], v[2]);
            acc[3] = fmaxf(acc[3], v[3]);
        }
        uint2v pw = { pk_bf16(acc[0], acc[1]), pk_bf16(acc[2], acc[3]) };
        const int wb = ((row * 128) + c4 * 8) ^ ((row & 7) << 4);
        *(uint2v*)(aw + wb) = pw;
    }

    const int key = (c4 & 7) << 4;
    short8 a0 = *(const short8*)(aw + ((c4 * 128 + qq * 16) ^ key));
    short8 a1 = *(const short8*)(aw + ((c4 * 128 + 64 + qq * 16) ^ key));

    f32x4 acc0 = {0,0,0,0}, acc1 = {0,0,0,0}, acc2 = {0,0,0,0}, acc3 = {0,0,0,0};
    acc0 = __builtin_amdgcn_mfma_f32_16x16x32_bf16(a0, bfr[0], acc0, 0, 0, 0);
    acc0 = __builtin_amdgcn_mfma_f32_16x16x32_bf16(a1, bfr[1], acc0, 0, 0, 0);
    acc1 = __builtin_amdgcn_mfma_f32_16x16x32_bf16(a0, bfr[2], acc1, 0, 0, 0);
    acc1 = __builtin_amdgcn_mfma_f32_16x16x32_bf16(a1, bfr[3], acc1, 0, 0, 0);
    acc2 = __builtin_amdgcn_mfma_f32_16x16x32_bf16(a0, bfr[4], acc2, 0, 0, 0);
    acc2 = __builtin_amdgcn_mfma_f32_16x16x32_bf16(a1, bfr[5], acc2, 0, 0, 0);
    acc3 = __builtin_amdgcn_mfma_f32_16x16x32_bf16(a0, bfr[6], acc3, 0, 0, 0);
    acc3 = __builtin_amdgcn_mfma_f32_16x16x32_bf16(a1, bfr[7], acc3, 0, 0, 0);

    float* yrow = yb + (size_t)(r0 + qq * 4) * CH + c4;
#define DO_CT(CT, ACC)                                                              \
    {                                                                               \
        yrow[0 * CH + CT * 16] = ACC[0];                                            \
        yrow[1 * CH + CT * 16] = ACC[1];                                            \
        yrow[2 * CH + CT * 16] = ACC[2];                                            \
        yrow[3 * CH + CT * 16] = ACC[3];                                            \
        float s1 = (ACC[0] + ACC[1]) + (ACC[2] + ACC[3]);                           \
        float s2 = (ACC[0]*ACC[0] + ACC[1]*ACC[1]) + (ACC[2]*ACC[2] + ACC[3]*ACC[3]); \
        s1 += __shfl_xor(s1, 16); s1 += __shfl_xor(s1, 32);                         \
        s2 += __shfl_xor(s2, 16); s2 += __shfl_xor(s2, 32);                         \
        if (lane < 16) {                                                            \
            atomicAdd(&bs1[CT * 16 + lane], s1);                                    \
            atomicAdd(&bs2[CT * 16 + lane], s2);                                    \
        }                                                                           \
    }
    DO_CT(0, acc0) DO_CT(1, acc1) DO_CT(2, acc2) DO_CT(3, acc3)
#undef DO_CT

    __syncthreads();
    if (threadIdx.x < 64)        atomicAdd(&stats[threadIdx.x], bs1[threadIdx.x]);
    else if (threadIdx.x < 128)  atomicAdd(&stats[threadIdx.x], bs2[threadIdx.x - 64]);
}

// ---- BN finalize ----
__global__ void k_finalize(const float* __restrict__ stats,
                           const float* __restrict__ gamma,
                           const float* __restrict__ beta,
                           float* __restrict__ sb)
{
    const int l = threadIdx.x;
    if (l >= CH) return;
    const float inv_n = 1.0f / (float)ROWS;
    float mean = stats[l] * inv_n;
    float ex2  = stats[64 + l] * inv_n;
    float var  = ex2 - mean * mean;
    float scale = gamma[l] * rsqrtf(var + EPS);
    sb[l]      = scale;
    sb[64 + l] = beta[l] - mean * scale;
}

// ---- in-place normalize ----
__global__ __launch_bounds__(256)
void k_norm(float* __restrict__ y, const float* __restrict__ sb)
{
    __shared__ float s[CH], b[CH];
    if (threadIdx.x < CH) {
        s[threadIdx.x] = sb[threadIdx.x];
        b[threadIdx.x] = sb[64 + threadIdx.x];
    }
    __syncthreads();

    float4* p = (float4*)y;
    const size_t ntot = (size_t)ROWS * CH / 4;
    size_t i = (size_t)blockIdx.x * blockDim.x + threadIdx.x;
    const size_t stride = (size_t)gridDim.x * blockDim.x;
    for (; i < ntot; i += stride) {
        float4 v = p[i];
        const int c0 = ((int)i & 15) * 4;
        v.x = fmaf(v.x, s[c0],     b[c0]);
        v.y = fmaf(v.y, s[c0 + 1], b[c0 + 1]);
        v.z = fmaf(v.z, s[c0 + 2], b[c0 + 2]);
        v.w = fmaf(v.w, s[c0 + 3], b[c0 + 3]);
        p[i] = v;
    }
}

extern "C" void kernel_launch(void* const* d_in, const int* in_sizes, int n_in,
                              void* d_out, int out_size, void* d_ws, size_t ws_size,
                              hipStream_t stream)
{
    const float* x     = (const float*)d_in[0];
    const int*   idx   = (const int*)d_in[1];
    const float* W     = (const float*)d_in[2];
    const float* gamma = (const float*)d_in[3];
    const float* beta  = (const float*)d_in[4];

    float*    y     = (float*)d_out;
    float*    stats = (float*)d_ws;                      // [0,64) sum, [64,128) sumsq
    float*    sb    = stats + 128;                       // scale / bias
    unsigned* wsb   = (unsigned*)(stats + 256);          // 8KB B-fragments
    unsigned* xb16  = (unsigned*)((char*)d_ws + 16384);  // 16.8MB bf16 x

    const size_t need = 16384 + (size_t)ROWS * CH * 2;

    hipMemsetAsync(stats, 0, 128 * sizeof(float), stream);
    k_prep<<<dim3(1), dim3(64), 0, stream>>>(W, wsb);

    if (ws_size >= need) {
        k_cvt<<<dim3(2048), dim3(256), 0, stream>>>(x, xb16);
        k_fused_bf16<2><<<dim3(1024), dim3(256), 0, stream>>>(xb16, idx, wsb, y, stats);
    } else {
        k_fused_f32<<<dim3(2048), dim3(256), 0, stream>>>(x, idx, wsb, y, stats);
    }

    k_finalize<<<dim3(1), dim3(64), 0, stream>>>(stats, gamma, beta, sb);
    k_norm<<<dim3(2048), dim3(256), 0, stream>>>(y, sb);
}